// Round 5
// baseline (120.590 us; speedup 1.0000x reference)
//
#include <hip/hip_runtime.h>

using u32 = unsigned int;
using u64 = unsigned long long;

static constexpr int NB  = 4;     // batch
static constexpr int NN  = 4096;  // nodes
static constexpr int KIN = 256;   // in features
static constexpr int FO  = 128;   // out features
static constexpr int NCH = 64;    // merge chunks per batch
static constexpr int CH  = NN / NCH;  // 64
static constexpr float SLOPE = 0.01f;

__device__ __forceinline__ float f4c(const float4& v, int kk) {
  switch (kk) { case 0: return v.x; case 1: return v.y; case 2: return v.z; default: return v.w; }
}

// monotone bijection f32 -> orderable u32 (no NaNs present)
__device__ __forceinline__ u32 f2key(float f) {
  const u32 b = __float_as_uint(f);
  return (b & 0x80000000u) ? ~b : (b | 0x80000000u);
}
__device__ __forceinline__ float key2f(u32 u) {
  const u32 b = (u & 0x80000000u) ? (u ^ 0x80000000u) : ~u;
  return __uint_as_float(b);
}

__device__ __forceinline__ u64 shfl_xor64(u64 v, int m) {
  const u32 lo = __shfl_xor((u32)(v & 0xffffffffu), m, 64);
  const u32 hi = __shfl_xor((u32)(v >> 32), m, 64);
  return ((u64)hi << 32) | (u64)lo;
}
__device__ __forceinline__ void cswap(u64& a, u64& b, bool up) {
  if ((a > b) == up) { const u64 tmp = a; a = b; b = tmp; }
}

// bitonic rounds j = min(k/2,128)..1 for phase k, data in registers.
// thread t holds elements i = 4t+r. Valid for any k >= 2.
__device__ __forceinline__ void reg_session(u64 e[4], int t, int k) {
  const int jstart = (k > 256) ? 128 : (k >> 1);
  for (int j = jstart; j >= 4; j >>= 1) {
    const int J = j >> 2;
    const bool up   = ((t & (k >> 2)) == 0);
    const bool lowr = ((t & J) == 0);
#pragma unroll
    for (int r = 0; r < 4; ++r) {
      const u64 o = shfl_xor64(e[r], J);
      const bool less = e[r] < o;              // keys unique (idx tie-break)
      e[r] = ((lowr == up) == less) ? e[r] : o;
    }
  }
  if (k >= 4) {
    const bool up = ((t & (k >> 2)) == 0);
    cswap(e[0], e[2], up); cswap(e[1], e[3], up);
  }
  {
    const bool up0 = (((4 * t)     & k) == 0);
    const bool up1 = (((4 * t + 2) & k) == 0);
    cswap(e[0], e[1], up0); cswap(e[2], e[3], up1);
  }
}

// ---------------- Kernel 1: feats = x @ W, fused f1/f2 ---------------------
// grid 512 x 256 thr. Tile M=32 x FO=128; per-thread 4x4 register block.
// K in 4 phases of 64, register double-buffered staging (loads of phase p+1
// issue before compute of phase p).
__global__ __launch_bounds__(256) void k1_gemm(const float* __restrict__ x,
                                               const float* __restrict__ W,
                                               const float* __restrict__ wl,
                                               const float* __restrict__ blp,
                                               const float* __restrict__ wr,
                                               const float* __restrict__ brp,
                                               float* __restrict__ feats,
                                               float* __restrict__ f1g,
                                               float* __restrict__ f2g) {
  __shared__ float xs[32][64];    // 8 KiB
  __shared__ float wsd[64][128];  // 32 KiB
  const int t = threadIdx.x;
  const int rg = t >> 5;          // 0..7  (row group of 4)
  const int cg = t & 31;          // 0..31 (col group of 4)
  const int row0 = blockIdx.x * 32;
  const int xr = t >> 4, xc4 = (t & 15) * 4;       // x-staging coords (i=0)
  const int xr2 = (t + 256) >> 4, xc42 = ((t + 256) & 15) * 4;
  float acc[4][4];
#pragma unroll
  for (int m = 0; m < 4; ++m)
#pragma unroll
    for (int n = 0; n < 4; ++n) acc[m][n] = 0.f;

  const float4* Wg = (const float4*)W;
  float4 wbuf[8], xbuf[2];
#pragma unroll
  for (int i = 0; i < 8; ++i) wbuf[i] = Wg[t + i * 256];
  xbuf[0] = *(const float4*)(x + (size_t)(row0 + xr) * KIN + xc4);
  xbuf[1] = *(const float4*)(x + (size_t)(row0 + xr2) * KIN + xc42);

  for (int ph = 0; ph < 4; ++ph) {
    if (ph) __syncthreads();   // previous compute done before overwrite
#pragma unroll
    for (int i = 0; i < 8; ++i) {
      const int v = t + i * 256;
      *(float4*)(&wsd[v >> 5][(v & 31) * 4]) = wbuf[i];
    }
    *(float4*)(&xs[xr][xc4])   = xbuf[0];
    *(float4*)(&xs[xr2][xc42]) = xbuf[1];
    __syncthreads();
    if (ph < 3) {
#pragma unroll
      for (int i = 0; i < 8; ++i) wbuf[i] = Wg[(ph + 1) * 2048 + t + i * 256];
      xbuf[0] = *(const float4*)(x + (size_t)(row0 + xr) * KIN + (ph + 1) * 64 + xc4);
      xbuf[1] = *(const float4*)(x + (size_t)(row0 + xr2) * KIN + (ph + 1) * 64 + xc42);
    }
    for (int k = 0; k < 64; k += 4) {
      float4 xv[4];
#pragma unroll
      for (int m = 0; m < 4; ++m) xv[m] = *(const float4*)(&xs[rg * 4 + m][k]);
#pragma unroll
      for (int kk = 0; kk < 4; ++kk) {
        const float4 wv = *(const float4*)(&wsd[k + kk][cg * 4]);
#pragma unroll
        for (int m = 0; m < 4; ++m) {
          const float xm = f4c(xv[m], kk);
          acc[m][0] = fmaf(xm, wv.x, acc[m][0]);
          acc[m][1] = fmaf(xm, wv.y, acc[m][1]);
          acc[m][2] = fmaf(xm, wv.z, acc[m][2]);
          acc[m][3] = fmaf(xm, wv.w, acc[m][3]);
        }
      }
    }
  }

  // write feats (float4 per row)
#pragma unroll
  for (int m = 0; m < 4; ++m) {
    float4 r; r.x = acc[m][0]; r.y = acc[m][1]; r.z = acc[m][2]; r.w = acc[m][3];
    *(float4*)(feats + (size_t)(row0 + rg * 4 + m) * FO + cg * 4) = r;
  }

  // fused f1/f2: reduce per-thread 4-col dots over the 32-lane cg group
  const float4 wlv = *(const float4*)(wl + cg * 4);
  const float4 wrv = *(const float4*)(wr + cg * 4);
  const float bl = blp[0], br = brp[0];
#pragma unroll
  for (int m = 0; m < 4; ++m) {
    float d1 = acc[m][0] * wlv.x + acc[m][1] * wlv.y + acc[m][2] * wlv.z + acc[m][3] * wlv.w;
    float d2 = acc[m][0] * wrv.x + acc[m][1] * wrv.y + acc[m][2] * wrv.z + acc[m][3] * wrv.w;
#pragma unroll
    for (int off = 1; off < 32; off <<= 1) {
      d1 += __shfl_xor(d1, off, 64);
      d2 += __shfl_xor(d2, off, 64);
    }
    if (cg == 0) {
      const int row = row0 + rg * 4 + m;
      f1g[row] = d1 + bl;
      f2g[row] = d2 + br;
    }
  }
}

// ---------------- Kernel 3a: hierarchical bitonic sorts + scans -------------
// grid 8 x 1024. task 0 (blocks 0-3): sort (f1, i) asc -> f1sort + i1sort +
// dual exp scans. task 1 (blocks 4-7): sort (f2, j) -> f2sort + jidxS.
__global__ __launch_bounds__(1024, 1) void k3a_sort(const float* __restrict__ f1g,
                                                    const float* __restrict__ f2g,
                                                    float* __restrict__ f1sort,
                                                    int* __restrict__ i1sort,
                                                    float* __restrict__ sc1,
                                                    float* __restrict__ sc2,
                                                    float* __restrict__ f2sort,
                                                    int* __restrict__ jidxS) {
  __shared__ u64 lds[NN];          // 32 KiB
  __shared__ float wsumA[16], wsumB[16];
  const int t = threadIdx.x;
  const int lane = t & 63, wv = t >> 6;
  const int b = blockIdx.x & 3;
  const int task = blockIdx.x >> 2;
  const int base = b * NN;
  const float* __restrict__ src = task ? f2g : f1g;

  u64 e[4];
#pragma unroll
  for (int r = 0; r < 4; ++r) {
    const int i = 4 * t + r;
    e[r] = ((u64)f2key(src[base + i]) << 32) | (u32)i;
  }

  // phases k = 2..256 entirely in registers/shuffles
  for (int k = 2; k <= 256; k <<= 1) reg_session(e, t, k);
#pragma unroll
  for (int r = 0; r < 4; ++r) lds[4 * t + r] = e[r];
  __syncthreads();

  // phases k = 512..4096: LDS rounds for j>=256, register tail for j<=128
  for (int k = 512; k <= NN; k <<= 1) {
    for (int j = k >> 1; j >= 256; j >>= 1) {
#pragma unroll
      for (int pp = 0; pp < 2; ++pp) {
        const int p = t + pp * 1024;
        const int i = ((p & ~(j - 1)) << 1) | (p & (j - 1));
        const int ix = i | j;
        const bool up = ((i & k) == 0);
        const u64 a = lds[i], c = lds[ix];
        if ((a > c) == up) { lds[i] = c; lds[ix] = a; }
      }
      __syncthreads();
    }
#pragma unroll
    for (int r = 0; r < 4; ++r) e[r] = lds[4 * t + r];
    reg_session(e, t, k);
    if (k < NN) {
#pragma unroll
      for (int r = 0; r < 4; ++r) lds[4 * t + r] = e[r];
      __syncthreads();
    }
  }
  // e[] now globally sorted ascending; thread t holds ranks 4t..4t+3.

  if (task == 0) {
    float kf[4], a[4], c[4];
#pragma unroll
    for (int r = 0; r < 4; ++r) {
      kf[r] = key2f((u32)(e[r] >> 32));
      f1sort[base + 4 * t + r] = kf[r];
      i1sort[base + 4 * t + r] = (int)(e[r] & 0xffffffffu);
      a[r] = expf(kf[r]);
      c[r] = expf(SLOPE * kf[r]);
    }
#pragma unroll
    for (int r = 1; r < 4; ++r) { a[r] += a[r - 1]; c[r] += c[r - 1]; }
    const float sa = a[3], sb = c[3];
    float pa = sa, pb = sb;
    for (int off = 1; off < 64; off <<= 1) {
      const float oa = __shfl_up(pa, off, 64);
      const float ob = __shfl_up(pb, off, 64);
      if (lane >= off) { pa += oa; pb += ob; }
    }
    if (lane == 63) { wsumA[wv] = pa; wsumB[wv] = pb; }
    __syncthreads();
    float wpa = 0.f, wpb = 0.f;
    for (int w2 = 0; w2 < wv; ++w2) { wpa += wsumA[w2]; wpb += wsumB[w2]; }
    const float basea = wpa + pa - sa, baseb = wpb + pb - sb;
#pragma unroll
    for (int r = 0; r < 4; ++r) {
      sc1[base + 4 * t + r] = basea + a[r];
      sc2[base + 4 * t + r] = baseb + c[r];
    }
  } else {
#pragma unroll
    for (int r = 0; r < 4; ++r) {
      f2sort[base + 4 * t + r] = key2f((u32)(e[r] >> 32));
      jidxS[base + 4 * t + r]  = (int)(e[r] & 0xffffffffu);
    }
  }
}

// ---------------- Kernel 3b: alpha/beta per sorted-j + emission schedule ----
// grid NB*8 x 512. Also emits, for sorted-f1 rank r (descending order pos =
// NN-1-r): rowS (original row), kpS (merge position, ascending in pos),
// e1S/e2S (exp factors).
__device__ __forceinline__ int lower_bound_s(const float* a, int n, float t) {
  int lo = 0, hi = n;
  while (lo < hi) {
    const int mid = (lo + hi) >> 1;
    if (a[mid] < t) lo = mid + 1; else hi = mid;
  }
  return lo;
}

__global__ __launch_bounds__(512) void k3b_ab(const float* __restrict__ f1sort,
                                              const int* __restrict__ i1sort,
                                              const float* __restrict__ sc1,
                                              const float* __restrict__ sc2,
                                              const float* __restrict__ f2sort,
                                              float* __restrict__ alphaS,
                                              float* __restrict__ betaS,
                                              int* __restrict__ rowS,
                                              int* __restrict__ kpS,
                                              float* __restrict__ e1S,
                                              float* __restrict__ e2S) {
  __shared__ float s_f1[NN];  // 16 KiB
  __shared__ float s_f2[NN];  // 16 KiB
  const int b = blockIdx.x >> 3;
  const int part = blockIdx.x & 7;
  const int base = b * NN;
  for (int i = threadIdx.x; i < NN; i += 512) {
    s_f1[i] = f1sort[base + i];
    s_f2[i] = f2sort[base + i];
  }
  __syncthreads();
  const int g = part * 512 + threadIdx.x;
  const float T1 = sc1[base + NN - 1];
  const float f1max = s_f1[NN - 1];
  {
    const float f2v = s_f2[g];
    const float m = f1max + f2v;
    const float M = (m >= 0.f) ? m : SLOPE * m;      // column max of leaky scores
    const int p = lower_bound_s(s_f1, NN, -f2v);     // first i with f1 >= -f2
    const float S1 = T1 - (p > 0 ? sc1[base + p - 1] : 0.f);
    const float S2 = (p > 0 ? sc2[base + p - 1] : 0.f);
    const float ea = expf(f2v - M);
    const float eb = expf(SLOPE * f2v - M);
    const float invD = 1.0f / (ea * S1 + eb * S2);
    alphaS[base + g] = ea * invD;
    betaS[base + g]  = eb * invD;
  }
  {
    const int r = g;                                 // sorted-f1 rank (asc)
    const float f1v = s_f1[r];
    const int kp = lower_bound_s(s_f2, NN, -f1v);    // first sorted-j with f2 >= -f1
    const int pos = NN - 1 - r;                      // descending f1 => kp ascending
    rowS[base + pos] = i1sort[base + r];
    kpS[base + pos]  = kp;
    e1S[base + pos]  = expf(f1v);
    e2S[base + pos]  = expf(SLOPE * f1v);
  }
}

// ---------------- Kernel 4a: per-chunk partial sums -------------------------
__global__ __launch_bounds__(128) void k4a_csum(const float* __restrict__ feats,
                                                const float* __restrict__ alphaS,
                                                const float* __restrict__ betaS,
                                                const int* __restrict__ jidxS,
                                                float* __restrict__ csumA,
                                                float* __restrict__ csumB) {
  const int b = blockIdx.x / NCH, c = blockIdx.x % NCH;
  const int o = threadIdx.x;
  const int base = b * NN + c * CH;
  const float* fb = feats + (size_t)b * NN * FO;
  float accA = 0.f, accB = 0.f;
#pragma unroll 4
  for (int q = 0; q < CH; ++q) {
    const int kk = base + q;
    const int j = jidxS[kk];
    const float fv = fb[(size_t)j * FO + o];
    accA = fmaf(alphaS[kk], fv, accA);
    accB = fmaf(betaS[kk], fv, accB);
  }
  csumA[(size_t)(b * NCH + c) * FO + o] = accA;
  csumB[(size_t)(b * NCH + c) * FO + o] = accB;
}

// ---------------- Kernel 4m: merge walk + output emission -------------------
// grid NB*NCH x 128 (thread = output column o). Block (b,c) walks sorted-j
// positions [c*CH, (c+1)*CH), maintaining running prefix (runA, runB) in
// registers; emits out rows whose kp falls at the current position.
__global__ __launch_bounds__(128) void k4m_merge(const float* __restrict__ feats,
                                                 const float* __restrict__ alphaS,
                                                 const float* __restrict__ betaS,
                                                 const int* __restrict__ jidxS,
                                                 const float* __restrict__ csumA,
                                                 const float* __restrict__ csumB,
                                                 const int* __restrict__ rowS,
                                                 const int* __restrict__ kpS,
                                                 const float* __restrict__ e1S,
                                                 const float* __restrict__ e2S,
                                                 float* __restrict__ out) {
  const int b = blockIdx.x / NCH, c = blockIdx.x % NCH;
  const int o = threadIdx.x;
  const int base = b * NN;

  // chunk prefix + totals from csums (L2-resident)
  float runA = 0.f, runB = 0.f, totA = 0.f, totB = 0.f;
#pragma unroll 4
  for (int c2 = 0; c2 < NCH; ++c2) {
    const float a  = csumA[(size_t)(b * NCH + c2) * FO + o];
    const float bb = csumB[(size_t)(b * NCH + c2) * FO + o];
    totA += a; totB += bb;
    if (c2 < c) { runA += a; runB += bb; }
  }

  // first emission rank with kp >= c*CH (kpS ascending)
  const int jj0 = c * CH;
  int lo = 0, hi = NN;
  while (lo < hi) {
    const int mid = (lo + hi) >> 1;
    if (kpS[base + mid] < jj0) lo = mid + 1; else hi = mid;
  }
  int r = base + lo;
  const int rend = base + NN;
  const float* fb = feats + (size_t)b * NN * FO;

  for (int jj = jj0; jj < jj0 + CH; ++jj) {
    while (r < rend && kpS[r] == jj) {
      const int row = rowS[r];
      out[(size_t)(base + row) * FO + o] =
          fmaf(e1S[r], totA - runA, e2S[r] * runB);
      ++r;
    }
    const int kk = base + jj;
    const int j = jidxS[kk];
    const float fv = fb[(size_t)j * FO + o];
    runA = fmaf(alphaS[kk], fv, runA);
    runB = fmaf(betaS[kk], fv, runB);
  }
  if (c == NCH - 1) {
    // rows with kp == NN (f1 so negative that all j are in the 0.01-branch)
    while (r < rend) {
      const int row = rowS[r];
      out[(size_t)(base + row) * FO + o] =
          fmaf(e1S[r], totA - runA, e2S[r] * runB);
      ++r;
    }
  }
}

extern "C" void kernel_launch(void* const* d_in, const int* in_sizes, int n_in,
                              void* d_out, int out_size, void* d_ws, size_t ws_size,
                              hipStream_t stream) {
  const float* x  = (const float*)d_in[0];
  const float* W  = (const float*)d_in[1];
  const float* wl = (const float*)d_in[2];
  const float* bl = (const float*)d_in[3];
  const float* wr = (const float*)d_in[4];
  const float* br = (const float*)d_in[5];
  float* out = (float*)d_out;

  float* ws = (float*)d_ws;
  float* feats  = ws; ws += NB * NN * FO;
  float* f1g    = ws; ws += NB * NN;
  float* f2g    = ws; ws += NB * NN;
  float* f1sort = ws; ws += NB * NN;
  float* f2sort = ws; ws += NB * NN;
  float* sc1    = ws; ws += NB * NN;
  float* sc2    = ws; ws += NB * NN;
  float* alphaS = ws; ws += NB * NN;
  float* betaS  = ws; ws += NB * NN;
  float* e1S    = ws; ws += NB * NN;
  float* e2S    = ws; ws += NB * NN;
  int* jidxS    = (int*)ws; ws += NB * NN;
  int* i1sort   = (int*)ws; ws += NB * NN;
  int* rowS     = (int*)ws; ws += NB * NN;
  int* kpS      = (int*)ws; ws += NB * NN;
  float* csumA  = ws; ws += NB * NCH * FO;
  float* csumB  = ws; ws += NB * NCH * FO;
  (void)in_sizes; (void)n_in; (void)out_size; (void)ws_size;

  hipLaunchKernelGGL(k1_gemm,   dim3(NB * NN / 32), dim3(256),  0, stream,
                     x, W, wl, bl, wr, br, feats, f1g, f2g);
  hipLaunchKernelGGL(k3a_sort,  dim3(8),            dim3(1024), 0, stream,
                     f1g, f2g, f1sort, i1sort, sc1, sc2, f2sort, jidxS);
  hipLaunchKernelGGL(k3b_ab,    dim3(NB * 8),       dim3(512),  0, stream,
                     f1sort, i1sort, sc1, sc2, f2sort, alphaS, betaS, rowS, kpS, e1S, e2S);
  hipLaunchKernelGGL(k4a_csum,  dim3(NB * NCH),     dim3(128),  0, stream,
                     feats, alphaS, betaS, jidxS, csumA, csumB);
  hipLaunchKernelGGL(k4m_merge, dim3(NB * NCH),     dim3(128),  0, stream,
                     feats, alphaS, betaS, jidxS, csumA, csumB, rowS, kpS, e1S, e2S, out);
}

// Round 6
// 99.387 us; speedup vs baseline: 1.2133x; 1.2133x over previous
//
#include <hip/hip_runtime.h>

using u32 = unsigned int;
using u64 = unsigned long long;

static constexpr int NB  = 4;     // batch
static constexpr int NN  = 4096;  // nodes
static constexpr int KIN = 256;   // in features
static constexpr int FO  = 128;   // out features
static constexpr int NCC = 64;    // coarse chunks per batch (64 positions each)
static constexpr int NFC = 512;   // fine chunks per batch (8 positions each)
static constexpr float SLOPE = 0.01f;

__device__ __forceinline__ float f4c(const float4& v, int kk) {
  switch (kk) { case 0: return v.x; case 1: return v.y; case 2: return v.z; default: return v.w; }
}

// monotone bijection f32 -> orderable u32 (no NaNs present)
__device__ __forceinline__ u32 f2key(float f) {
  const u32 b = __float_as_uint(f);
  return (b & 0x80000000u) ? ~b : (b | 0x80000000u);
}
__device__ __forceinline__ float key2f(u32 u) {
  const u32 b = (u & 0x80000000u) ? (u ^ 0x80000000u) : ~u;
  return __uint_as_float(b);
}

__device__ __forceinline__ u64 shfl_xor64(u64 v, int m) {
  const u32 lo = __shfl_xor((u32)(v & 0xffffffffu), m, 64);
  const u32 hi = __shfl_xor((u32)(v >> 32), m, 64);
  return ((u64)hi << 32) | (u64)lo;
}
__device__ __forceinline__ void cswap(u64& a, u64& b, bool up) {
  if ((a > b) == up) { const u64 tmp = a; a = b; b = tmp; }
}

// bitonic rounds j = min(k/2,128)..1 for phase k, data in registers.
// thread t holds elements i = 4t+r. Valid for any k >= 2.
__device__ __forceinline__ void reg_session(u64 e[4], int t, int k) {
  const int jstart = (k > 256) ? 128 : (k >> 1);
  for (int j = jstart; j >= 4; j >>= 1) {
    const int J = j >> 2;
    const bool up   = ((t & (k >> 2)) == 0);
    const bool lowr = ((t & J) == 0);
#pragma unroll
    for (int r = 0; r < 4; ++r) {
      const u64 o = shfl_xor64(e[r], J);
      const bool less = e[r] < o;              // keys unique (idx tie-break)
      e[r] = ((lowr == up) == less) ? e[r] : o;
    }
  }
  if (k >= 4) {
    const bool up = ((t & (k >> 2)) == 0);
    cswap(e[0], e[2], up); cswap(e[1], e[3], up);
  }
  {
    const bool up0 = (((4 * t)     & k) == 0);
    const bool up1 = (((4 * t + 2) & k) == 0);
    cswap(e[0], e[1], up0); cswap(e[2], e[3], up1);
  }
}

// ---------------- Kernel 1: feats = x @ W, fused f1/f2 ---------------------
// grid 512 x 256 thr. Tile M=32 x FO=128; per-thread 4x4 register block.
// K in 4 phases of 64, register double-buffered staging.
__global__ __launch_bounds__(256) void k1_gemm(const float* __restrict__ x,
                                               const float* __restrict__ W,
                                               const float* __restrict__ wl,
                                               const float* __restrict__ blp,
                                               const float* __restrict__ wr,
                                               const float* __restrict__ brp,
                                               float* __restrict__ feats,
                                               float* __restrict__ f1g,
                                               float* __restrict__ f2g) {
  __shared__ float xs[32][64];    // 8 KiB
  __shared__ float wsd[64][128];  // 32 KiB
  const int t = threadIdx.x;
  const int rg = t >> 5;          // 0..7  (row group of 4)
  const int cg = t & 31;          // 0..31 (col group of 4)
  const int row0 = blockIdx.x * 32;
  const int xr = t >> 4, xc4 = (t & 15) * 4;       // x-staging coords (i=0)
  const int xr2 = (t + 256) >> 4, xc42 = ((t + 256) & 15) * 4;
  float acc[4][4];
#pragma unroll
  for (int m = 0; m < 4; ++m)
#pragma unroll
    for (int n = 0; n < 4; ++n) acc[m][n] = 0.f;

  const float4* Wg = (const float4*)W;
  float4 wbuf[8], xbuf[2];
#pragma unroll
  for (int i = 0; i < 8; ++i) wbuf[i] = Wg[t + i * 256];
  xbuf[0] = *(const float4*)(x + (size_t)(row0 + xr) * KIN + xc4);
  xbuf[1] = *(const float4*)(x + (size_t)(row0 + xr2) * KIN + xc42);

  for (int ph = 0; ph < 4; ++ph) {
    if (ph) __syncthreads();   // previous compute done before overwrite
#pragma unroll
    for (int i = 0; i < 8; ++i) {
      const int v = t + i * 256;
      *(float4*)(&wsd[v >> 5][(v & 31) * 4]) = wbuf[i];
    }
    *(float4*)(&xs[xr][xc4])   = xbuf[0];
    *(float4*)(&xs[xr2][xc42]) = xbuf[1];
    __syncthreads();
    if (ph < 3) {
#pragma unroll
      for (int i = 0; i < 8; ++i) wbuf[i] = Wg[(ph + 1) * 2048 + t + i * 256];
      xbuf[0] = *(const float4*)(x + (size_t)(row0 + xr) * KIN + (ph + 1) * 64 + xc4);
      xbuf[1] = *(const float4*)(x + (size_t)(row0 + xr2) * KIN + (ph + 1) * 64 + xc42);
    }
    for (int k = 0; k < 64; k += 4) {
      float4 xv[4];
#pragma unroll
      for (int m = 0; m < 4; ++m) xv[m] = *(const float4*)(&xs[rg * 4 + m][k]);
#pragma unroll
      for (int kk = 0; kk < 4; ++kk) {
        const float4 wv = *(const float4*)(&wsd[k + kk][cg * 4]);
#pragma unroll
        for (int m = 0; m < 4; ++m) {
          const float xm = f4c(xv[m], kk);
          acc[m][0] = fmaf(xm, wv.x, acc[m][0]);
          acc[m][1] = fmaf(xm, wv.y, acc[m][1]);
          acc[m][2] = fmaf(xm, wv.z, acc[m][2]);
          acc[m][3] = fmaf(xm, wv.w, acc[m][3]);
        }
      }
    }
  }

  // write feats (float4 per row)
#pragma unroll
  for (int m = 0; m < 4; ++m) {
    float4 r; r.x = acc[m][0]; r.y = acc[m][1]; r.z = acc[m][2]; r.w = acc[m][3];
    *(float4*)(feats + (size_t)(row0 + rg * 4 + m) * FO + cg * 4) = r;
  }

  // fused f1/f2: reduce per-thread 4-col dots over the 32-lane cg group
  const float4 wlv = *(const float4*)(wl + cg * 4);
  const float4 wrv = *(const float4*)(wr + cg * 4);
  const float bl = blp[0], br = brp[0];
#pragma unroll
  for (int m = 0; m < 4; ++m) {
    float d1 = acc[m][0] * wlv.x + acc[m][1] * wlv.y + acc[m][2] * wlv.z + acc[m][3] * wlv.w;
    float d2 = acc[m][0] * wrv.x + acc[m][1] * wrv.y + acc[m][2] * wrv.z + acc[m][3] * wrv.w;
#pragma unroll
    for (int off = 1; off < 32; off <<= 1) {
      d1 += __shfl_xor(d1, off, 64);
      d2 += __shfl_xor(d2, off, 64);
    }
    if (cg == 0) {
      const int row = row0 + rg * 4 + m;
      f1g[row] = d1 + bl;
      f2g[row] = d2 + br;
    }
  }
}

// ---------------- Kernel 3a: hierarchical bitonic sorts + scans -------------
// grid 8 x 1024. task 0 (blocks 0-3): sort f1 asc -> f1sort + dual exp scans.
// task 1 (blocks 4-7): sort (f2, j) -> f2sort + jidxS.
__global__ __launch_bounds__(1024, 1) void k3a_sort(const float* __restrict__ f1g,
                                                    const float* __restrict__ f2g,
                                                    float* __restrict__ f1sort,
                                                    float* __restrict__ sc1,
                                                    float* __restrict__ sc2,
                                                    float* __restrict__ f2sort,
                                                    int* __restrict__ jidxS) {
  __shared__ u64 lds[NN];          // 32 KiB
  __shared__ float wsumA[16], wsumB[16];
  const int t = threadIdx.x;
  const int lane = t & 63, wv = t >> 6;
  const int b = blockIdx.x & 3;
  const int task = blockIdx.x >> 2;
  const int base = b * NN;
  const float* __restrict__ src = task ? f2g : f1g;

  u64 e[4];
#pragma unroll
  for (int r = 0; r < 4; ++r) {
    const int i = 4 * t + r;
    e[r] = ((u64)f2key(src[base + i]) << 32) | (u32)i;
  }

  // phases k = 2..256 entirely in registers/shuffles
  for (int k = 2; k <= 256; k <<= 1) reg_session(e, t, k);
#pragma unroll
  for (int r = 0; r < 4; ++r) lds[4 * t + r] = e[r];
  __syncthreads();

  // phases k = 512..4096: LDS rounds for j>=256, register tail for j<=128
  for (int k = 512; k <= NN; k <<= 1) {
    for (int j = k >> 1; j >= 256; j >>= 1) {
#pragma unroll
      for (int pp = 0; pp < 2; ++pp) {
        const int p = t + pp * 1024;
        const int i = ((p & ~(j - 1)) << 1) | (p & (j - 1));
        const int ix = i | j;
        const bool up = ((i & k) == 0);
        const u64 a = lds[i], c = lds[ix];
        if ((a > c) == up) { lds[i] = c; lds[ix] = a; }
      }
      __syncthreads();
    }
#pragma unroll
    for (int r = 0; r < 4; ++r) e[r] = lds[4 * t + r];
    reg_session(e, t, k);
    if (k < NN) {
#pragma unroll
      for (int r = 0; r < 4; ++r) lds[4 * t + r] = e[r];
      __syncthreads();
    }
  }
  // e[] now globally sorted ascending; thread t holds ranks 4t..4t+3.

  if (task == 0) {
    float kf[4], a[4], c[4];
#pragma unroll
    for (int r = 0; r < 4; ++r) {
      kf[r] = key2f((u32)(e[r] >> 32));
      f1sort[base + 4 * t + r] = kf[r];
      a[r] = expf(kf[r]);
      c[r] = expf(SLOPE * kf[r]);
    }
#pragma unroll
    for (int r = 1; r < 4; ++r) { a[r] += a[r - 1]; c[r] += c[r - 1]; }
    const float sa = a[3], sb = c[3];
    float pa = sa, pb = sb;
    for (int off = 1; off < 64; off <<= 1) {
      const float oa = __shfl_up(pa, off, 64);
      const float ob = __shfl_up(pb, off, 64);
      if (lane >= off) { pa += oa; pb += ob; }
    }
    if (lane == 63) { wsumA[wv] = pa; wsumB[wv] = pb; }
    __syncthreads();
    float wpa = 0.f, wpb = 0.f;
    for (int w2 = 0; w2 < wv; ++w2) { wpa += wsumA[w2]; wpb += wsumB[w2]; }
    const float basea = wpa + pa - sa, baseb = wpb + pb - sb;
#pragma unroll
    for (int r = 0; r < 4; ++r) {
      sc1[base + 4 * t + r] = basea + a[r];
      sc2[base + 4 * t + r] = baseb + c[r];
    }
  } else {
#pragma unroll
    for (int r = 0; r < 4; ++r) {
      f2sort[base + 4 * t + r] = key2f((u32)(e[r] >> 32));
      jidxS[base + 4 * t + r]  = (int)(e[r] & 0xffffffffu);
    }
  }
}

// ---------------- Kernel 3b: alpha/beta per sorted-j, kpos/E1/E2 per row ----
__device__ __forceinline__ int lower_bound_s(const float* a, int n, float t) {
  int lo = 0, hi = n;
  while (lo < hi) {
    const int mid = (lo + hi) >> 1;
    if (a[mid] < t) lo = mid + 1; else hi = mid;
  }
  return lo;
}

__global__ __launch_bounds__(512) void k3b_ab(const float* __restrict__ f1sort,
                                              const float* __restrict__ sc1,
                                              const float* __restrict__ sc2,
                                              const float* __restrict__ f2sort,
                                              const float* __restrict__ f1g,
                                              float* __restrict__ alphaS,
                                              float* __restrict__ betaS,
                                              int* __restrict__ kposA,
                                              float* __restrict__ E1g,
                                              float* __restrict__ E2g) {
  __shared__ float s_f1[NN];  // 16 KiB
  __shared__ float s_f2[NN];  // 16 KiB
  const int b = blockIdx.x >> 3;
  const int part = blockIdx.x & 7;
  const int base = b * NN;
  for (int i = threadIdx.x; i < NN; i += 512) {
    s_f1[i] = f1sort[base + i];
    s_f2[i] = f2sort[base + i];
  }
  __syncthreads();
  const int g = part * 512 + threadIdx.x;
  const float T1 = sc1[base + NN - 1];
  const float f1max = s_f1[NN - 1];
  {
    const float f2v = s_f2[g];
    const float m = f1max + f2v;
    const float M = (m >= 0.f) ? m : SLOPE * m;      // column max of leaky scores
    const int p = lower_bound_s(s_f1, NN, -f2v);     // first i with f1 >= -f2
    const float S1 = T1 - (p > 0 ? sc1[base + p - 1] : 0.f);
    const float S2 = (p > 0 ? sc2[base + p - 1] : 0.f);
    const float ea = expf(f2v - M);
    const float eb = expf(SLOPE * f2v - M);
    const float invD = 1.0f / (ea * S1 + eb * S2);
    alphaS[base + g] = ea * invD;
    betaS[base + g]  = eb * invD;
  }
  {
    const float f1v = f1g[base + g];
    kposA[base + g] = lower_bound_s(s_f2, NN, -f1v); // first sorted-j with f2 >= -f1
    E1g[base + g] = expf(f1v);
    E2g[base + g] = expf(SLOPE * f1v);
  }
}

// ---------------- Kernel 4a: fine prefix sums within coarse chunks ----------
// grid NB*NCC x 128. Block (b,cc) walks sorted-j [cc*64, cc*64+64); every 8
// steps writes the intra-coarse inclusive prefix (finePre). All gather
// addresses known up-front -> full ILP pipelining.
__global__ __launch_bounds__(128) void k4a_csum(const float* __restrict__ feats,
                                                const float* __restrict__ alphaS,
                                                const float* __restrict__ betaS,
                                                const int* __restrict__ jidxS,
                                                float* __restrict__ finePreA,
                                                float* __restrict__ finePreB) {
  const int b = blockIdx.x >> 6, cc = blockIdx.x & 63;
  const int o = threadIdx.x;
  const int base = b * NN + cc * 64;
  const float* fb = feats + (size_t)b * NN * FO;
  float accA = 0.f, accB = 0.f;
  for (int f = 0; f < 8; ++f) {
#pragma unroll
    for (int q = 0; q < 8; ++q) {
      const int kk = base + f * 8 + q;
      const int j = jidxS[kk];
      const float fv = fb[(size_t)j * FO + o];
      accA = fmaf(alphaS[kk], fv, accA);
      accB = fmaf(betaS[kk], fv, accB);
    }
    finePreA[(size_t)(b * NFC + cc * 8 + f) * FO + o] = accA;
    finePreB[(size_t)(b * NFC + cc * 8 + f) * FO + o] = accB;
  }
}

// ---------------- Kernel 4c: exclusive prefix over coarse sums --------------
// grid NB x 128. coarPref[c] = sum of coarse chunks < c; entry NCC = total.
__global__ __launch_bounds__(128) void k4c_coar(const float* __restrict__ finePreA,
                                                const float* __restrict__ finePreB,
                                                float* __restrict__ coarA,
                                                float* __restrict__ coarB) {
  const int b = blockIdx.x;
  const int o = threadIdx.x;
  float runA = 0.f, runB = 0.f;
  for (int c = 0; c < NCC; ++c) {
    coarA[(size_t)(b * (NCC + 1) + c) * FO + o] = runA;
    coarB[(size_t)(b * (NCC + 1) + c) * FO + o] = runB;
    runA += finePreA[(size_t)(b * NFC + c * 8 + 7) * FO + o];
    runB += finePreB[(size_t)(b * NFC + c * 8 + 7) * FO + o];
  }
  coarA[(size_t)(b * (NCC + 1) + NCC) * FO + o] = runA;   // total
  coarB[(size_t)(b * (NCC + 1) + NCC) * FO + o] = runB;
}

// ---------------- Kernel 5: per-row combine (f32 out) -----------------------
// out[i,:] = E1_i*(totA - runA(kp_i)) + E2_i*runB(kp_i)
// runX(kp) = coarPref[kp>>6] + finePre[fine-1 within coarse] + <=7 gathers.
__global__ __launch_bounds__(256) void k5_out(const float* __restrict__ feats,
                                              const float* __restrict__ alphaS,
                                              const float* __restrict__ betaS,
                                              const int* __restrict__ jidxS,
                                              const float* __restrict__ finePreA,
                                              const float* __restrict__ finePreB,
                                              const float* __restrict__ coarA,
                                              const float* __restrict__ coarB,
                                              const int* __restrict__ kposA,
                                              const float* __restrict__ E1g,
                                              const float* __restrict__ E2g,
                                              float* __restrict__ out) {
  const int t = threadIdx.x;
  const int row = blockIdx.x * 2 + (t >> 7);
  const int o = t & 127;
  const int b = row >> 12;  // NN = 4096
  const int base = b * NN;
  const int kp = kposA[row];
  const float e1 = E1g[row], e2 = E2g[row];
  const int c   = kp >> 6;        // 0..64
  const int fi  = (kp >> 3) & 7;  // fine chunk within coarse
  const int rem = kp & 7;

  float runA = coarA[(size_t)(b * (NCC + 1) + c) * FO + o];
  float runB = coarB[(size_t)(b * (NCC + 1) + c) * FO + o];
  const float totA = coarA[(size_t)(b * (NCC + 1) + NCC) * FO + o];
  if (fi > 0) {
    runA += finePreA[(size_t)(b * NFC + c * 8 + fi - 1) * FO + o];
    runB += finePreB[(size_t)(b * NFC + c * 8 + fi - 1) * FO + o];
  }
  const float* fb = feats + (size_t)b * NN * FO;
  for (int q = kp - rem; q < kp; ++q) {
    const int kk = base + q;
    const int j = jidxS[kk];
    const float fv = fb[(size_t)j * FO + o];
    runA = fmaf(alphaS[kk], fv, runA);
    runB = fmaf(betaS[kk], fv, runB);
  }
  out[(size_t)row * FO + o] = fmaf(e1, totA - runA, e2 * runB);
}

extern "C" void kernel_launch(void* const* d_in, const int* in_sizes, int n_in,
                              void* d_out, int out_size, void* d_ws, size_t ws_size,
                              hipStream_t stream) {
  const float* x  = (const float*)d_in[0];
  const float* W  = (const float*)d_in[1];
  const float* wl = (const float*)d_in[2];
  const float* bl = (const float*)d_in[3];
  const float* wr = (const float*)d_in[4];
  const float* br = (const float*)d_in[5];
  float* out = (float*)d_out;

  float* ws = (float*)d_ws;
  float* feats    = ws; ws += NB * NN * FO;
  float* f1g      = ws; ws += NB * NN;
  float* f2g      = ws; ws += NB * NN;
  float* f1sort   = ws; ws += NB * NN;
  float* f2sort   = ws; ws += NB * NN;
  float* sc1      = ws; ws += NB * NN;
  float* sc2      = ws; ws += NB * NN;
  float* alphaS   = ws; ws += NB * NN;
  float* betaS    = ws; ws += NB * NN;
  float* E1g      = ws; ws += NB * NN;
  float* E2g      = ws; ws += NB * NN;
  int* jidxS      = (int*)ws; ws += NB * NN;
  int* kposA      = (int*)ws; ws += NB * NN;
  float* finePreA = ws; ws += NB * NFC * FO;
  float* finePreB = ws; ws += NB * NFC * FO;
  float* coarA    = ws; ws += NB * (NCC + 1) * FO;
  float* coarB    = ws; ws += NB * (NCC + 1) * FO;
  (void)in_sizes; (void)n_in; (void)out_size; (void)ws_size;

  hipLaunchKernelGGL(k1_gemm,  dim3(NB * NN / 32), dim3(256),  0, stream,
                     x, W, wl, bl, wr, br, feats, f1g, f2g);
  hipLaunchKernelGGL(k3a_sort, dim3(8),            dim3(1024), 0, stream,
                     f1g, f2g, f1sort, sc1, sc2, f2sort, jidxS);
  hipLaunchKernelGGL(k3b_ab,   dim3(NB * 8),       dim3(512),  0, stream,
                     f1sort, sc1, sc2, f2sort, f1g, alphaS, betaS, kposA, E1g, E2g);
  hipLaunchKernelGGL(k4a_csum, dim3(NB * NCC),     dim3(128),  0, stream,
                     feats, alphaS, betaS, jidxS, finePreA, finePreB);
  hipLaunchKernelGGL(k4c_coar, dim3(NB),           dim3(128),  0, stream,
                     finePreA, finePreB, coarA, coarB);
  hipLaunchKernelGGL(k5_out,   dim3(NB * NN / 2),  dim3(256),  0, stream,
                     feats, alphaS, betaS, jidxS, finePreA, finePreB,
                     coarA, coarB, kposA, E1g, E2g, out);
}

// Round 7
// 84.450 us; speedup vs baseline: 1.4280x; 1.1769x over previous
//
#include <hip/hip_runtime.h>

using u16 = unsigned short;
using u32 = unsigned int;
using u64 = unsigned long long;

typedef short bf16x8 __attribute__((ext_vector_type(8)));
typedef float f32x4 __attribute__((ext_vector_type(4)));

static constexpr int NB  = 4;     // batch
static constexpr int NN  = 4096;  // nodes
static constexpr int KIN = 256;   // in features
static constexpr int FO  = 128;   // out features
static constexpr int NROW = NB * NN;  // 16384 total rows
static constexpr int NCC = 64;    // coarse chunks per batch
static constexpr int NFC = 512;   // fine chunks per batch (8 positions each)
static constexpr float SLOPE = 0.01f;

// ---- bf16 helpers (RNE, no NaN inputs) ----
__device__ __forceinline__ u16 f2bf(float f) {
  const u32 u = __float_as_uint(f);
  return (u16)((u + 0x7fffu + ((u >> 16) & 1u)) >> 16);
}
__device__ __forceinline__ float bf2f(u16 h) {
  return __uint_as_float(((u32)h) << 16);
}

// monotone bijection f32 -> orderable u32 (no NaNs present)
__device__ __forceinline__ u32 f2key(float f) {
  const u32 b = __float_as_uint(f);
  return (b & 0x80000000u) ? ~b : (b | 0x80000000u);
}
__device__ __forceinline__ float key2f(u32 u) {
  const u32 b = (u & 0x80000000u) ? (u ^ 0x80000000u) : ~u;
  return __uint_as_float(b);
}

__device__ __forceinline__ u64 shfl_xor64(u64 v, int m) {
  const u32 lo = __shfl_xor((u32)(v & 0xffffffffu), m, 64);
  const u32 hi = __shfl_xor((u32)(v >> 32), m, 64);
  return ((u64)hi << 32) | (u64)lo;
}
__device__ __forceinline__ void cswap(u64& a, u64& b, bool up) {
  if ((a > b) == up) { const u64 tmp = a; a = b; b = tmp; }
}

// bitonic rounds j = min(k/2,128)..1 for phase k, data in registers.
__device__ __forceinline__ void reg_session(u64 e[4], int t, int k) {
  const int jstart = (k > 256) ? 128 : (k >> 1);
  for (int j = jstart; j >= 4; j >>= 1) {
    const int J = j >> 2;
    const bool up   = ((t & (k >> 2)) == 0);
    const bool lowr = ((t & J) == 0);
#pragma unroll
    for (int r = 0; r < 4; ++r) {
      const u64 o = shfl_xor64(e[r], J);
      const bool less = e[r] < o;              // keys unique (idx tie-break)
      e[r] = ((lowr == up) == less) ? e[r] : o;
    }
  }
  if (k >= 4) {
    const bool up = ((t & (k >> 2)) == 0);
    cswap(e[0], e[2], up); cswap(e[1], e[3], up);
  }
  {
    const bool up0 = (((4 * t)     & k) == 0);
    const bool up1 = (((4 * t + 2) & k) == 0);
    cswap(e[0], e[1], up0); cswap(e[2], e[3], up1);
  }
}

// ---------------- Kernel 0: u = W @ w, Wh/Wl bf16 split transposed ---------
// grid 128 x 256. blocks 0-63: u_l/u_r (wave per k-row).
// blocks 64-127: whT/wloT [col][k] bf16 hi/lo split of W.
__global__ __launch_bounds__(256) void k0_prep(const float* __restrict__ W,
                                               const float* __restrict__ wl,
                                               const float* __restrict__ wr,
                                               float* __restrict__ u_l,
                                               float* __restrict__ u_r,
                                               u16* __restrict__ whT,
                                               u16* __restrict__ wloT) {
  const int t = threadIdx.x;
  const int blk = blockIdx.x;
  if (blk < 64) {
    const int k = blk * 4 + (t >> 6);
    const int lane = t & 63;
    const float w0 = W[k * FO + lane], w1 = W[k * FO + 64 + lane];
    float a1 = w0 * wl[lane] + w1 * wl[64 + lane];
    float a2 = w0 * wr[lane] + w1 * wr[64 + lane];
#pragma unroll
    for (int off = 1; off < 64; off <<= 1) {
      a1 += __shfl_xor(a1, off, 64);
      a2 += __shfl_xor(a2, off, 64);
    }
    if (lane == 0) { u_l[k] = a1; u_r[k] = a2; }
  } else {
#pragma unroll
    for (int e = 0; e < 2; ++e) {
      const int idx = (blk - 64) * 512 + t + e * 256;  // 0..32767
      const int col = idx >> 8, k = idx & 255;
      const float v = W[k * FO + col];
      const u16 h = f2bf(v);
      whT[col * KIN + k]  = h;
      wloT[col * KIN + k] = f2bf(v - bf2f(h));
    }
  }
}

// ---------------- Kernel 1a: x split to bf16 hi/lo + exact f1/f2 -----------
// grid 1024 x 256 (4 waves x 4 rows each). f1 = x . u_l + bl (exact f32).
__global__ __launch_bounds__(256) void k1a_conv(const float* __restrict__ x,
                                                const float* __restrict__ u_l,
                                                const float* __restrict__ u_r,
                                                const float* __restrict__ blp,
                                                const float* __restrict__ brp,
                                                u16* __restrict__ xh,
                                                u16* __restrict__ xl,
                                                float* __restrict__ f1g,
                                                float* __restrict__ f2g) {
  const int t = threadIdx.x, w = t >> 6, lane = t & 63;
  const float4 ul = *(const float4*)(u_l + 4 * lane);
  const float4 ur = *(const float4*)(u_r + 4 * lane);
  const float bl = blp[0], br = brp[0];
#pragma unroll
  for (int rr = 0; rr < 4; ++rr) {
    const int row = blockIdx.x * 16 + w * 4 + rr;
    const float4 xv = *(const float4*)(x + (size_t)row * KIN + 4 * lane);
    // split
    ushort4 hx, lx;
    hx.x = f2bf(xv.x); lx.x = f2bf(xv.x - bf2f(hx.x));
    hx.y = f2bf(xv.y); lx.y = f2bf(xv.y - bf2f(hx.y));
    hx.z = f2bf(xv.z); lx.z = f2bf(xv.z - bf2f(hx.z));
    hx.w = f2bf(xv.w); lx.w = f2bf(xv.w - bf2f(hx.w));
    *(ushort4*)(xh + (size_t)row * KIN + 4 * lane) = hx;
    *(ushort4*)(xl + (size_t)row * KIN + 4 * lane) = lx;
    float d1 = xv.x * ul.x + xv.y * ul.y + xv.z * ul.z + xv.w * ul.w;
    float d2 = xv.x * ur.x + xv.y * ur.y + xv.z * ur.z + xv.w * ur.w;
#pragma unroll
    for (int off = 1; off < 64; off <<= 1) {
      d1 += __shfl_xor(d1, off, 64);
      d2 += __shfl_xor(d2, off, 64);
    }
    if (lane == 0) {
      f1g[row] = d1 + bl;
      f2g[row] = d2 + br;
    }
  }
}

// ---------------- Kernel 1b: feats = xh.Wh + xh.Wl + xl.Wh (MFMA) ----------
// grid 256 x 256. BM=64, BN=128, BK=64, 4 waves in 2x2; wave-tile 32x64
// (2x4 frags of 16x16). LDS rows padded to 72 bf16 (144 B) -> 2-way banks.
__global__ __launch_bounds__(256) void k1b_mfma(const u16* __restrict__ xh,
                                                const u16* __restrict__ xl,
                                                const u16* __restrict__ whT,
                                                const u16* __restrict__ wloT,
                                                float* __restrict__ feats) {
  __shared__ u16 axh[64][72];
  __shared__ u16 axl[64][72];
  __shared__ u16 bwh[128][72];
  __shared__ u16 bwl[128][72];
  const int t = threadIdx.x;
  const int w = t >> 6, lane = t & 63;
  const int wm = w >> 1, wn = w & 1;
  const int row0 = blockIdx.x * 64;
  f32x4 acc[2][4];
#pragma unroll
  for (int m = 0; m < 2; ++m)
#pragma unroll
    for (int n = 0; n < 4; ++n) acc[m][n] = (f32x4)0.f;

  for (int it = 0; it < 4; ++it) {
    __syncthreads();
    // stage x tiles: 64 rows x 64 k, 16B chunks
#pragma unroll
    for (int i = 0; i < 2; ++i) {
      const int v = t + i * 256;           // 0..511
      const int r = v >> 3, c = v & 7;
      const size_t src = (size_t)(row0 + r) * KIN + it * 64 + c * 8;
      *(bf16x8*)(&axh[r][c * 8]) = *(const bf16x8*)(xh + src);
      *(bf16x8*)(&axl[r][c * 8]) = *(const bf16x8*)(xl + src);
    }
    // stage W tiles: 128 cols x 64 k
#pragma unroll
    for (int i = 0; i < 4; ++i) {
      const int v = t + i * 256;           // 0..1023
      const int col = v >> 3, c = v & 7;
      const size_t src = (size_t)col * KIN + it * 64 + c * 8;
      *(bf16x8*)(&bwh[col][c * 8]) = *(const bf16x8*)(whT + src);
      *(bf16x8*)(&bwl[col][c * 8]) = *(const bf16x8*)(wloT + src);
    }
    __syncthreads();
#pragma unroll
    for (int kk = 0; kk < 2; ++kk) {
      const int kb = kk * 32 + (lane >> 4) * 8;
      bf16x8 ah[2], al[2], bh[4], blo[4];
#pragma unroll
      for (int m = 0; m < 2; ++m) {
        const int r = wm * 32 + m * 16 + (lane & 15);
        ah[m] = *(const bf16x8*)(&axh[r][kb]);
        al[m] = *(const bf16x8*)(&axl[r][kb]);
      }
#pragma unroll
      for (int n = 0; n < 4; ++n) {
        const int cidx = wn * 64 + n * 16 + (lane & 15);
        bh[n]  = *(const bf16x8*)(&bwh[cidx][kb]);
        blo[n] = *(const bf16x8*)(&bwl[cidx][kb]);
      }
#pragma unroll
      for (int m = 0; m < 2; ++m)
#pragma unroll
        for (int n = 0; n < 4; ++n) {
          acc[m][n] = __builtin_amdgcn_mfma_f32_16x16x32_bf16(ah[m], bh[n],  acc[m][n], 0, 0, 0);
          acc[m][n] = __builtin_amdgcn_mfma_f32_16x16x32_bf16(ah[m], blo[n], acc[m][n], 0, 0, 0);
          acc[m][n] = __builtin_amdgcn_mfma_f32_16x16x32_bf16(al[m], bh[n],  acc[m][n], 0, 0, 0);
        }
    }
  }
  // epilogue: C frag map col=lane&15, row=(lane>>4)*4+r
#pragma unroll
  for (int m = 0; m < 2; ++m) {
    const int rb = row0 + wm * 32 + m * 16 + (lane >> 4) * 4;
    const int cb = wn * 64 + (lane & 15);
#pragma unroll
    for (int n = 0; n < 4; ++n)
#pragma unroll
      for (int r = 0; r < 4; ++r)
        feats[(size_t)(rb + r) * FO + cb + n * 16] = acc[m][n][r];
  }
}

// ---------------- Kernel 3a: hierarchical bitonic sorts + scans -------------
__global__ __launch_bounds__(1024, 1) void k3a_sort(const float* __restrict__ f1g,
                                                    const float* __restrict__ f2g,
                                                    float* __restrict__ f1sort,
                                                    float* __restrict__ sc1,
                                                    float* __restrict__ sc2,
                                                    float* __restrict__ f2sort,
                                                    int* __restrict__ jidxS) {
  __shared__ u64 lds[NN];          // 32 KiB
  __shared__ float wsumA[16], wsumB[16];
  const int t = threadIdx.x;
  const int lane = t & 63, wv = t >> 6;
  const int b = blockIdx.x & 3;
  const int task = blockIdx.x >> 2;
  const int base = b * NN;
  const float* __restrict__ src = task ? f2g : f1g;

  u64 e[4];
#pragma unroll
  for (int r = 0; r < 4; ++r) {
    const int i = 4 * t + r;
    e[r] = ((u64)f2key(src[base + i]) << 32) | (u32)i;
  }

  for (int k = 2; k <= 256; k <<= 1) reg_session(e, t, k);
#pragma unroll
  for (int r = 0; r < 4; ++r) lds[4 * t + r] = e[r];
  __syncthreads();

  for (int k = 512; k <= NN; k <<= 1) {
    for (int j = k >> 1; j >= 256; j >>= 1) {
#pragma unroll
      for (int pp = 0; pp < 2; ++pp) {
        const int p = t + pp * 1024;
        const int i = ((p & ~(j - 1)) << 1) | (p & (j - 1));
        const int ix = i | j;
        const bool up = ((i & k) == 0);
        const u64 a = lds[i], c = lds[ix];
        if ((a > c) == up) { lds[i] = c; lds[ix] = a; }
      }
      __syncthreads();
    }
#pragma unroll
    for (int r = 0; r < 4; ++r) e[r] = lds[4 * t + r];
    reg_session(e, t, k);
    if (k < NN) {
#pragma unroll
      for (int r = 0; r < 4; ++r) lds[4 * t + r] = e[r];
      __syncthreads();
    }
  }

  if (task == 0) {
    float kf[4], a[4], c[4];
#pragma unroll
    for (int r = 0; r < 4; ++r) {
      kf[r] = key2f((u32)(e[r] >> 32));
      f1sort[base + 4 * t + r] = kf[r];
      a[r] = expf(kf[r]);
      c[r] = expf(SLOPE * kf[r]);
    }
#pragma unroll
    for (int r = 1; r < 4; ++r) { a[r] += a[r - 1]; c[r] += c[r - 1]; }
    const float sa = a[3], sb = c[3];
    float pa = sa, pb = sb;
    for (int off = 1; off < 64; off <<= 1) {
      const float oa = __shfl_up(pa, off, 64);
      const float ob = __shfl_up(pb, off, 64);
      if (lane >= off) { pa += oa; pb += ob; }
    }
    if (lane == 63) { wsumA[wv] = pa; wsumB[wv] = pb; }
    __syncthreads();
    float wpa = 0.f, wpb = 0.f;
    for (int w2 = 0; w2 < wv; ++w2) { wpa += wsumA[w2]; wpb += wsumB[w2]; }
    const float basea = wpa + pa - sa, baseb = wpb + pb - sb;
#pragma unroll
    for (int r = 0; r < 4; ++r) {
      sc1[base + 4 * t + r] = basea + a[r];
      sc2[base + 4 * t + r] = baseb + c[r];
    }
  } else {
#pragma unroll
    for (int r = 0; r < 4; ++r) {
      f2sort[base + 4 * t + r] = key2f((u32)(e[r] >> 32));
      jidxS[base + 4 * t + r]  = (int)(e[r] & 0xffffffffu);
    }
  }
}

// ---------------- Kernel 3b: alpha/beta per sorted-j, kpos/E1/E2 per row ----
__device__ __forceinline__ int lower_bound_s(const float* a, int n, float t) {
  int lo = 0, hi = n;
  while (lo < hi) {
    const int mid = (lo + hi) >> 1;
    if (a[mid] < t) lo = mid + 1; else hi = mid;
  }
  return lo;
}

__global__ __launch_bounds__(512) void k3b_ab(const float* __restrict__ f1sort,
                                              const float* __restrict__ sc1,
                                              const float* __restrict__ sc2,
                                              const float* __restrict__ f2sort,
                                              const float* __restrict__ f1g,
                                              float* __restrict__ alphaS,
                                              float* __restrict__ betaS,
                                              int* __restrict__ kposA,
                                              float* __restrict__ E1g,
                                              float* __restrict__ E2g) {
  __shared__ float s_f1[NN];  // 16 KiB
  __shared__ float s_f2[NN];  // 16 KiB
  const int b = blockIdx.x >> 3;
  const int part = blockIdx.x & 7;
  const int base = b * NN;
  for (int i = threadIdx.x; i < NN; i += 512) {
    s_f1[i] = f1sort[base + i];
    s_f2[i] = f2sort[base + i];
  }
  __syncthreads();
  const int g = part * 512 + threadIdx.x;
  const float T1 = sc1[base + NN - 1];
  const float f1max = s_f1[NN - 1];
  {
    const float f2v = s_f2[g];
    const float m = f1max + f2v;
    const float M = (m >= 0.f) ? m : SLOPE * m;      // column max of leaky scores
    const int p = lower_bound_s(s_f1, NN, -f2v);     // first i with f1 >= -f2
    const float S1 = T1 - (p > 0 ? sc1[base + p - 1] : 0.f);
    const float S2 = (p > 0 ? sc2[base + p - 1] : 0.f);
    const float ea = expf(f2v - M);
    const float eb = expf(SLOPE * f2v - M);
    const float invD = 1.0f / (ea * S1 + eb * S2);
    alphaS[base + g] = ea * invD;
    betaS[base + g]  = eb * invD;
  }
  {
    const float f1v = f1g[base + g];
    kposA[base + g] = lower_bound_s(s_f2, NN, -f1v); // first sorted-j with f2 >= -f1
    E1g[base + g] = expf(f1v);
    E2g[base + g] = expf(SLOPE * f1v);
  }
}

// ---------------- Kernel 4a: fine prefix sums within coarse chunks ----------
__global__ __launch_bounds__(128) void k4a_csum(const float* __restrict__ feats,
                                                const float* __restrict__ alphaS,
                                                const float* __restrict__ betaS,
                                                const int* __restrict__ jidxS,
                                                float* __restrict__ finePreA,
                                                float* __restrict__ finePreB) {
  const int b = blockIdx.x >> 6, cc = blockIdx.x & 63;
  const int o = threadIdx.x;
  const int base = b * NN + cc * 64;
  const float* fb = feats + (size_t)b * NN * FO;
  float accA = 0.f, accB = 0.f;
  for (int f = 0; f < 8; ++f) {
#pragma unroll
    for (int q = 0; q < 8; ++q) {
      const int kk = base + f * 8 + q;
      const int j = jidxS[kk];
      const float fv = fb[(size_t)j * FO + o];
      accA = fmaf(alphaS[kk], fv, accA);
      accB = fmaf(betaS[kk], fv, accB);
    }
    finePreA[(size_t)(b * NFC + cc * 8 + f) * FO + o] = accA;
    finePreB[(size_t)(b * NFC + cc * 8 + f) * FO + o] = accB;
  }
}

// ---------------- Kernel 4c: exclusive prefix over coarse sums --------------
__global__ __launch_bounds__(128) void k4c_coar(const float* __restrict__ finePreA,
                                                const float* __restrict__ finePreB,
                                                float* __restrict__ coarA,
                                                float* __restrict__ coarB) {
  const int b = blockIdx.x;
  const int o = threadIdx.x;
  float runA = 0.f, runB = 0.f;
  for (int c = 0; c < NCC; ++c) {
    coarA[(size_t)(b * (NCC + 1) + c) * FO + o] = runA;
    coarB[(size_t)(b * (NCC + 1) + c) * FO + o] = runB;
    runA += finePreA[(size_t)(b * NFC + c * 8 + 7) * FO + o];
    runB += finePreB[(size_t)(b * NFC + c * 8 + 7) * FO + o];
  }
  coarA[(size_t)(b * (NCC + 1) + NCC) * FO + o] = runA;   // total
  coarB[(size_t)(b * (NCC + 1) + NCC) * FO + o] = runB;
}

// ---------------- Kernel 5: per-row combine (f32 out) -----------------------
__global__ __launch_bounds__(256) void k5_out(const float* __restrict__ feats,
                                              const float* __restrict__ alphaS,
                                              const float* __restrict__ betaS,
                                              const int* __restrict__ jidxS,
                                              const float* __restrict__ finePreA,
                                              const float* __restrict__ finePreB,
                                              const float* __restrict__ coarA,
                                              const float* __restrict__ coarB,
                                              const int* __restrict__ kposA,
                                              const float* __restrict__ E1g,
                                              const float* __restrict__ E2g,
                                              float* __restrict__ out) {
  const int t = threadIdx.x;
  const int row = blockIdx.x * 2 + (t >> 7);
  const int o = t & 127;
  const int b = row >> 12;  // NN = 4096
  const int base = b * NN;
  const int kp = kposA[row];
  const float e1 = E1g[row], e2 = E2g[row];
  const int c   = kp >> 6;        // 0..64
  const int fi  = (kp >> 3) & 7;  // fine chunk within coarse
  const int rem = kp & 7;

  float runA = coarA[(size_t)(b * (NCC + 1) + c) * FO + o];
  float runB = coarB[(size_t)(b * (NCC + 1) + c) * FO + o];
  const float totA = coarA[(size_t)(b * (NCC + 1) + NCC) * FO + o];
  if (fi > 0) {
    runA += finePreA[(size_t)(b * NFC + c * 8 + fi - 1) * FO + o];
    runB += finePreB[(size_t)(b * NFC + c * 8 + fi - 1) * FO + o];
  }
  const float* fb = feats + (size_t)b * NN * FO;
  for (int q = kp - rem; q < kp; ++q) {
    const int kk = base + q;
    const int j = jidxS[kk];
    const float fv = fb[(size_t)j * FO + o];
    runA = fmaf(alphaS[kk], fv, runA);
    runB = fmaf(betaS[kk], fv, runB);
  }
  out[(size_t)row * FO + o] = fmaf(e1, totA - runA, e2 * runB);
}

extern "C" void kernel_launch(void* const* d_in, const int* in_sizes, int n_in,
                              void* d_out, int out_size, void* d_ws, size_t ws_size,
                              hipStream_t stream) {
  const float* x  = (const float*)d_in[0];
  const float* W  = (const float*)d_in[1];
  const float* wl = (const float*)d_in[2];
  const float* bl = (const float*)d_in[3];
  const float* wr = (const float*)d_in[4];
  const float* br = (const float*)d_in[5];
  float* out = (float*)d_out;

  float* ws = (float*)d_ws;
  float* feats    = ws; ws += NROW * FO;
  float* f1g      = ws; ws += NROW;
  float* f2g      = ws; ws += NROW;
  float* f1sort   = ws; ws += NROW;
  float* f2sort   = ws; ws += NROW;
  float* sc1      = ws; ws += NROW;
  float* sc2      = ws; ws += NROW;
  float* alphaS   = ws; ws += NROW;
  float* betaS    = ws; ws += NROW;
  float* E1g      = ws; ws += NROW;
  float* E2g      = ws; ws += NROW;
  int* jidxS      = (int*)ws; ws += NROW;
  int* kposA      = (int*)ws; ws += NROW;
  float* finePreA = ws; ws += NB * NFC * FO;
  float* finePreB = ws; ws += NB * NFC * FO;
  float* coarA    = ws; ws += NB * (NCC + 1) * FO;
  float* coarB    = ws; ws += NB * (NCC + 1) * FO;
  float* u_l      = ws; ws += KIN;
  float* u_r      = ws; ws += KIN;
  u16* xh   = (u16*)ws; ws += NROW * KIN / 2;   // bf16 [16384][256]
  u16* xl   = (u16*)ws; ws += NROW * KIN / 2;
  u16* whT  = (u16*)ws; ws += FO * KIN / 2;     // bf16 [128 col][256 k]
  u16* wloT = (u16*)ws; ws += FO * KIN / 2;
  (void)in_sizes; (void)n_in; (void)out_size; (void)ws_size;

  hipLaunchKernelGGL(k0_prep,  dim3(128),          dim3(256),  0, stream,
                     W, wl, wr, u_l, u_r, whT, wloT);
  hipLaunchKernelGGL(k1a_conv, dim3(NROW / 16),    dim3(256),  0, stream,
                     x, u_l, u_r, bl, br, xh, xl, f1g, f2g);
  hipLaunchKernelGGL(k1b_mfma, dim3(NROW / 64),    dim3(256),  0, stream,
                     xh, xl, whT, wloT, feats);
  hipLaunchKernelGGL(k3a_sort, dim3(8),            dim3(1024), 0, stream,
                     f1g, f2g, f1sort, sc1, sc2, f2sort, jidxS);
  hipLaunchKernelGGL(k3b_ab,   dim3(NB * 8),       dim3(512),  0, stream,
                     f1sort, sc1, sc2, f2sort, f1g, alphaS, betaS, kposA, E1g, E2g);
  hipLaunchKernelGGL(k4a_csum, dim3(NB * NCC),     dim3(128),  0, stream,
                     feats, alphaS, betaS, jidxS, finePreA, finePreB);
  hipLaunchKernelGGL(k4c_coar, dim3(NB),           dim3(128),  0, stream,
                     finePreA, finePreB, coarA, coarB);
  hipLaunchKernelGGL(k5_out,   dim3(NROW / 2),     dim3(256),  0, stream,
                     feats, alphaS, betaS, jidxS, finePreA, finePreB,
                     coarA, coarB, kposA, E1g, E2g, out);
}

// Round 8
// 68.508 us; speedup vs baseline: 1.7602x; 1.2327x over previous
//
#include <hip/hip_runtime.h>

using u16 = unsigned short;
using u32 = unsigned int;
using u64 = unsigned long long;

typedef short bf16x8 __attribute__((ext_vector_type(8)));
typedef float f32x4 __attribute__((ext_vector_type(4)));

static constexpr int NB  = 4;     // batch
static constexpr int NN  = 4096;  // nodes
static constexpr int KIN = 256;   // in features
static constexpr int FO  = 128;   // out features
static constexpr int NROW = NB * NN;  // 16384 total rows
static constexpr int NCC = 64;    // coarse chunks per batch (64 positions each)
static constexpr float SLOPE = 0.01f;

// ---- bf16 helpers (RNE, no NaN inputs) ----
__device__ __forceinline__ u16 f2bf(float f) {
  const u32 u = __float_as_uint(f);
  return (u16)((u + 0x7fffu + ((u >> 16) & 1u)) >> 16);
}
__device__ __forceinline__ float bf2f(u16 h) {
  return __uint_as_float(((u32)h) << 16);
}
__device__ __forceinline__ float dot4(const float4& a, const float4& b) {
  return a.x * b.x + a.y * b.y + a.z * b.z + a.w * b.w;
}

// monotone bijection f32 -> orderable u32 (no NaNs present)
__device__ __forceinline__ u32 f2key(float f) {
  const u32 b = __float_as_uint(f);
  return (b & 0x80000000u) ? ~b : (b | 0x80000000u);
}
__device__ __forceinline__ float key2f(u32 u) {
  const u32 b = (u & 0x80000000u) ? (u ^ 0x80000000u) : ~u;
  return __uint_as_float(b);
}

__device__ __forceinline__ u64 shfl_xor64(u64 v, int m) {
  const u32 lo = __shfl_xor((u32)(v & 0xffffffffu), m, 64);
  const u32 hi = __shfl_xor((u32)(v >> 32), m, 64);
  return ((u64)hi << 32) | (u64)lo;
}
__device__ __forceinline__ void cswap(u64& a, u64& b, bool up) {
  if ((a > b) == up) { const u64 tmp = a; a = b; b = tmp; }
}

// bitonic rounds j = min(k/2,128)..1 for phase k, data in registers.
__device__ __forceinline__ void reg_session(u64 e[4], int t, int k) {
  const int jstart = (k > 256) ? 128 : (k >> 1);
  for (int j = jstart; j >= 4; j >>= 1) {
    const int J = j >> 2;
    const bool up   = ((t & (k >> 2)) == 0);
    const bool lowr = ((t & J) == 0);
#pragma unroll
    for (int r = 0; r < 4; ++r) {
      const u64 o = shfl_xor64(e[r], J);
      const bool less = e[r] < o;              // keys unique (idx tie-break)
      e[r] = ((lowr == up) == less) ? e[r] : o;
    }
  }
  if (k >= 4) {
    const bool up = ((t & (k >> 2)) == 0);
    cswap(e[0], e[2], up); cswap(e[1], e[3], up);
  }
  {
    const bool up0 = (((4 * t)     & k) == 0);
    const bool up1 = (((4 * t + 2) & k) == 0);
    cswap(e[0], e[1], up0); cswap(e[2], e[3], up1);
  }
}

// ---------------- Kernel 0: u = W @ w, Wh/Wl bf16 split transposed ---------
__global__ __launch_bounds__(256) void k0_prep(const float* __restrict__ W,
                                               const float* __restrict__ wl,
                                               const float* __restrict__ wr,
                                               float* __restrict__ u_l,
                                               float* __restrict__ u_r,
                                               u16* __restrict__ whT,
                                               u16* __restrict__ wloT) {
  const int t = threadIdx.x;
  const int blk = blockIdx.x;
  if (blk < 64) {
    const int k = blk * 4 + (t >> 6);
    const int lane = t & 63;
    const float w0 = W[k * FO + lane], w1 = W[k * FO + 64 + lane];
    float a1 = w0 * wl[lane] + w1 * wl[64 + lane];
    float a2 = w0 * wr[lane] + w1 * wr[64 + lane];
#pragma unroll
    for (int off = 1; off < 64; off <<= 1) {
      a1 += __shfl_xor(a1, off, 64);
      a2 += __shfl_xor(a2, off, 64);
    }
    if (lane == 0) { u_l[k] = a1; u_r[k] = a2; }
  } else {
#pragma unroll
    for (int e = 0; e < 2; ++e) {
      const int idx = (blk - 64) * 512 + t + e * 256;  // 0..32767
      const int col = idx >> 8, k = idx & 255;
      const float v = W[k * FO + col];
      const u16 h = f2bf(v);
      whT[col * KIN + k]  = h;
      wloT[col * KIN + k] = f2bf(v - bf2f(h));
    }
  }
}

// ---------------- Kernel 1: fused x-load -> f1/f2 + split-bf16 MFMA feats --
// grid 256 x 256. BM=64, BN=128, BK=64, 4 waves 2x2; wave-tile 32x64.
// x staged f32->hi/lo bf16 in-register; f1/f2 = exact f32 matvec vs u_l/u_r
// accumulated during staging, 8-lane shfl reduce at end.
__global__ __launch_bounds__(256) void k1_fused(const float* __restrict__ x,
                                                const u16* __restrict__ whT,
                                                const u16* __restrict__ wloT,
                                                const float* __restrict__ u_l,
                                                const float* __restrict__ u_r,
                                                const float* __restrict__ blp,
                                                const float* __restrict__ brp,
                                                float* __restrict__ feats,
                                                float* __restrict__ f1g,
                                                float* __restrict__ f2g) {
  __shared__ u16 axh[64][72];
  __shared__ u16 axl[64][72];
  __shared__ u16 bwh[128][72];
  __shared__ u16 bwl[128][72];
  const int t = threadIdx.x;
  const int w = t >> 6, lane = t & 63;
  const int wm = w >> 1, wn = w & 1;
  const int row0 = blockIdx.x * 64;
  const int xr = t >> 3, xc = t & 7;   // staging: rows xr & xr+32, k-chunk xc
  f32x4 acc[2][4];
#pragma unroll
  for (int m = 0; m < 2; ++m)
#pragma unroll
    for (int n = 0; n < 4; ++n) acc[m][n] = (f32x4)0.f;

  float d1a = 0.f, d2a = 0.f, d1b = 0.f, d2b = 0.f;  // f1/f2 partials
  float4 xa0, xa1, xb0, xb1;
  bf16x8 wh_[4], wl_[4];

  // prologue prefetch (it = 0)
  {
    const float* pa = x + (size_t)(row0 + xr) * KIN + xc * 8;
    const float* pb = x + (size_t)(row0 + xr + 32) * KIN + xc * 8;
    xa0 = *(const float4*)pa; xa1 = *(const float4*)(pa + 4);
    xb0 = *(const float4*)pb; xb1 = *(const float4*)(pb + 4);
#pragma unroll
    for (int i = 0; i < 4; ++i) {
      const int v = t + i * 256;
      const int col = v >> 3, c = v & 7;
      wh_[i] = *(const bf16x8*)(whT + (size_t)col * KIN + c * 8);
      wl_[i] = *(const bf16x8*)(wloT + (size_t)col * KIN + c * 8);
    }
  }

  for (int it = 0; it < 4; ++it) {
    if (it) __syncthreads();   // previous compute done before overwrite
    // f1/f2 partial dots from current f32 x regs
    {
      const float4 ul0 = *(const float4*)(u_l + it * 64 + xc * 8);
      const float4 ul1 = *(const float4*)(u_l + it * 64 + xc * 8 + 4);
      const float4 ur0 = *(const float4*)(u_r + it * 64 + xc * 8);
      const float4 ur1 = *(const float4*)(u_r + it * 64 + xc * 8 + 4);
      d1a += dot4(xa0, ul0) + dot4(xa1, ul1);
      d2a += dot4(xa0, ur0) + dot4(xa1, ur1);
      d1b += dot4(xb0, ul0) + dot4(xb1, ul1);
      d2b += dot4(xb0, ur0) + dot4(xb1, ur1);
    }
    // convert + ds_write x tiles
    {
      float va[8] = {xa0.x, xa0.y, xa0.z, xa0.w, xa1.x, xa1.y, xa1.z, xa1.w};
      float vb[8] = {xb0.x, xb0.y, xb0.z, xb0.w, xb1.x, xb1.y, xb1.z, xb1.w};
      bf16x8 ha, la, hb, lb;
#pragma unroll
      for (int q = 0; q < 8; ++q) {
        const u16 h1 = f2bf(va[q]);
        ha[q] = (short)h1; la[q] = (short)f2bf(va[q] - bf2f(h1));
        const u16 h2 = f2bf(vb[q]);
        hb[q] = (short)h2; lb[q] = (short)f2bf(vb[q] - bf2f(h2));
      }
      *(bf16x8*)(&axh[xr][xc * 8]) = ha;
      *(bf16x8*)(&axl[xr][xc * 8]) = la;
      *(bf16x8*)(&axh[xr + 32][xc * 8]) = hb;
      *(bf16x8*)(&axl[xr + 32][xc * 8]) = lb;
    }
    // ds_write W tiles
#pragma unroll
    for (int i = 0; i < 4; ++i) {
      const int v = t + i * 256;
      const int col = v >> 3, c = v & 7;
      *(bf16x8*)(&bwh[col][c * 8]) = wh_[i];
      *(bf16x8*)(&bwl[col][c * 8]) = wl_[i];
    }
    __syncthreads();
    // prefetch next iter (overlaps MFMA below)
    if (it < 3) {
      const float* pa = x + (size_t)(row0 + xr) * KIN + (it + 1) * 64 + xc * 8;
      const float* pb = x + (size_t)(row0 + xr + 32) * KIN + (it + 1) * 64 + xc * 8;
      xa0 = *(const float4*)pa; xa1 = *(const float4*)(pa + 4);
      xb0 = *(const float4*)pb; xb1 = *(const float4*)(pb + 4);
#pragma unroll
      for (int i = 0; i < 4; ++i) {
        const int v = t + i * 256;
        const int col = v >> 3, c = v & 7;
        wh_[i] = *(const bf16x8*)(whT + (size_t)col * KIN + (it + 1) * 64 + c * 8);
        wl_[i] = *(const bf16x8*)(wloT + (size_t)col * KIN + (it + 1) * 64 + c * 8);
      }
    }
    // MFMA: feats += xh.Wh + xh.Wl + xl.Wh
#pragma unroll
    for (int kk = 0; kk < 2; ++kk) {
      const int kb = kk * 32 + (lane >> 4) * 8;
      bf16x8 ah[2], al[2], bh[4], blo[4];
#pragma unroll
      for (int m = 0; m < 2; ++m) {
        const int r = wm * 32 + m * 16 + (lane & 15);
        ah[m] = *(const bf16x8*)(&axh[r][kb]);
        al[m] = *(const bf16x8*)(&axl[r][kb]);
      }
#pragma unroll
      for (int n = 0; n < 4; ++n) {
        const int cidx = wn * 64 + n * 16 + (lane & 15);
        bh[n]  = *(const bf16x8*)(&bwh[cidx][kb]);
        blo[n] = *(const bf16x8*)(&bwl[cidx][kb]);
      }
#pragma unroll
      for (int m = 0; m < 2; ++m)
#pragma unroll
        for (int n = 0; n < 4; ++n) {
          acc[m][n] = __builtin_amdgcn_mfma_f32_16x16x32_bf16(ah[m], bh[n],  acc[m][n], 0, 0, 0);
          acc[m][n] = __builtin_amdgcn_mfma_f32_16x16x32_bf16(ah[m], blo[n], acc[m][n], 0, 0, 0);
          acc[m][n] = __builtin_amdgcn_mfma_f32_16x16x32_bf16(al[m], bh[n],  acc[m][n], 0, 0, 0);
        }
    }
  }

  // feats epilogue: C frag map col=lane&15, row=(lane>>4)*4+r
#pragma unroll
  for (int m = 0; m < 2; ++m) {
    const int rb = row0 + wm * 32 + m * 16 + (lane >> 4) * 4;
    const int cb = wn * 64 + (lane & 15);
#pragma unroll
    for (int n = 0; n < 4; ++n)
#pragma unroll
      for (int r = 0; r < 4; ++r)
        feats[(size_t)(rb + r) * FO + cb + n * 16] = acc[m][n][r];
  }

  // f1/f2 epilogue: reduce 8-lane groups (threads sharing row xr)
#pragma unroll
  for (int off = 1; off < 8; off <<= 1) {
    d1a += __shfl_xor(d1a, off, 64);
    d2a += __shfl_xor(d2a, off, 64);
    d1b += __shfl_xor(d1b, off, 64);
    d2b += __shfl_xor(d2b, off, 64);
  }
  if ((t & 7) == 0) {
    const float bl = blp[0], br = brp[0];
    f1g[row0 + xr] = d1a + bl;
    f2g[row0 + xr] = d2a + br;
    f1g[row0 + xr + 32] = d1b + bl;
    f2g[row0 + xr + 32] = d2b + br;
  }
}

// ---------------- Kernel 3a: hierarchical bitonic sorts + scans -------------
__global__ __launch_bounds__(1024, 1) void k3a_sort(const float* __restrict__ f1g,
                                                    const float* __restrict__ f2g,
                                                    float* __restrict__ f1sort,
                                                    float* __restrict__ sc1,
                                                    float* __restrict__ sc2,
                                                    float* __restrict__ f2sort,
                                                    int* __restrict__ jidxS) {
  __shared__ u64 lds[NN];          // 32 KiB
  __shared__ float wsumA[16], wsumB[16];
  const int t = threadIdx.x;
  const int lane = t & 63, wv = t >> 6;
  const int b = blockIdx.x & 3;
  const int task = blockIdx.x >> 2;
  const int base = b * NN;
  const float* __restrict__ src = task ? f2g : f1g;

  u64 e[4];
#pragma unroll
  for (int r = 0; r < 4; ++r) {
    const int i = 4 * t + r;
    e[r] = ((u64)f2key(src[base + i]) << 32) | (u32)i;
  }

  for (int k = 2; k <= 256; k <<= 1) reg_session(e, t, k);
#pragma unroll
  for (int r = 0; r < 4; ++r) lds[4 * t + r] = e[r];
  __syncthreads();

  for (int k = 512; k <= NN; k <<= 1) {
    for (int j = k >> 1; j >= 256; j >>= 1) {
#pragma unroll
      for (int pp = 0; pp < 2; ++pp) {
        const int p = t + pp * 1024;
        const int i = ((p & ~(j - 1)) << 1) | (p & (j - 1));
        const int ix = i | j;
        const bool up = ((i & k) == 0);
        const u64 a = lds[i], c = lds[ix];
        if ((a > c) == up) { lds[i] = c; lds[ix] = a; }
      }
      __syncthreads();
    }
#pragma unroll
    for (int r = 0; r < 4; ++r) e[r] = lds[4 * t + r];
    reg_session(e, t, k);
    if (k < NN) {
#pragma unroll
      for (int r = 0; r < 4; ++r) lds[4 * t + r] = e[r];
      __syncthreads();
    }
  }

  if (task == 0) {
    float kf[4], a[4], c[4];
#pragma unroll
    for (int r = 0; r < 4; ++r) {
      kf[r] = key2f((u32)(e[r] >> 32));
      f1sort[base + 4 * t + r] = kf[r];
      a[r] = expf(kf[r]);
      c[r] = expf(SLOPE * kf[r]);
    }
#pragma unroll
    for (int r = 1; r < 4; ++r) { a[r] += a[r - 1]; c[r] += c[r - 1]; }
    const float sa = a[3], sb = c[3];
    float pa = sa, pb = sb;
    for (int off = 1; off < 64; off <<= 1) {
      const float oa = __shfl_up(pa, off, 64);
      const float ob = __shfl_up(pb, off, 64);
      if (lane >= off) { pa += oa; pb += ob; }
    }
    if (lane == 63) { wsumA[wv] = pa; wsumB[wv] = pb; }
    __syncthreads();
    float wpa = 0.f, wpb = 0.f;
    for (int w2 = 0; w2 < wv; ++w2) { wpa += wsumA[w2]; wpb += wsumB[w2]; }
    const float basea = wpa + pa - sa, baseb = wpb + pb - sb;
#pragma unroll
    for (int r = 0; r < 4; ++r) {
      sc1[base + 4 * t + r] = basea + a[r];
      sc2[base + 4 * t + r] = baseb + c[r];
    }
  } else {
#pragma unroll
    for (int r = 0; r < 4; ++r) {
      f2sort[base + 4 * t + r] = key2f((u32)(e[r] >> 32));
      jidxS[base + 4 * t + r]  = (int)(e[r] & 0xffffffffu);
    }
  }
}

// ---------------- Kernel 3b: alpha/beta per sorted-j, kpos/E1/E2 per row ----
__device__ __forceinline__ int lower_bound_s(const float* a, int n, float t) {
  int lo = 0, hi = n;
  while (lo < hi) {
    const int mid = (lo + hi) >> 1;
    if (a[mid] < t) lo = mid + 1; else hi = mid;
  }
  return lo;
}

__global__ __launch_bounds__(512) void k3b_ab(const float* __restrict__ f1sort,
                                              const float* __restrict__ sc1,
                                              const float* __restrict__ sc2,
                                              const float* __restrict__ f2sort,
                                              const float* __restrict__ f1g,
                                              float* __restrict__ alphaS,
                                              float* __restrict__ betaS,
                                              int* __restrict__ kposA,
                                              float* __restrict__ E1g,
                                              float* __restrict__ E2g) {
  __shared__ float s_f1[NN];  // 16 KiB
  __shared__ float s_f2[NN];  // 16 KiB
  const int b = blockIdx.x >> 3;
  const int part = blockIdx.x & 7;
  const int base = b * NN;
  for (int i = threadIdx.x; i < NN; i += 512) {
    s_f1[i] = f1sort[base + i];
    s_f2[i] = f2sort[base + i];
  }
  __syncthreads();
  const int g = part * 512 + threadIdx.x;
  const float T1 = sc1[base + NN - 1];
  const float f1max = s_f1[NN - 1];
  {
    const float f2v = s_f2[g];
    const float m = f1max + f2v;
    const float M = (m >= 0.f) ? m : SLOPE * m;      // column max of leaky scores
    const int p = lower_bound_s(s_f1, NN, -f2v);     // first i with f1 >= -f2
    const float S1 = T1 - (p > 0 ? sc1[base + p - 1] : 0.f);
    const float S2 = (p > 0 ? sc2[base + p - 1] : 0.f);
    const float ea = expf(f2v - M);
    const float eb = expf(SLOPE * f2v - M);
    const float invD = 1.0f / (ea * S1 + eb * S2);
    alphaS[base + g] = ea * invD;
    betaS[base + g]  = eb * invD;
  }
  {
    const float f1v = f1g[base + g];
    kposA[base + g] = lower_bound_s(s_f2, NN, -f1v); // first sorted-j with f2 >= -f1
    E1g[base + g] = expf(f1v);
    E2g[base + g] = expf(SLOPE * f1v);
  }
}

// ---------------- Kernel 4a: per-position inclusive prefixes ----------------
// grid NB*NCC x 128. Block (b,cc) walks sorted-j [cc*64, cc*64+64), writing
// the intra-chunk inclusive prefix at EVERY position (unroll-8 gather ILP).
__global__ __launch_bounds__(128) void k4a_pref(const float* __restrict__ feats,
                                                const float* __restrict__ alphaS,
                                                const float* __restrict__ betaS,
                                                const int* __restrict__ jidxS,
                                                float* __restrict__ finePreA,
                                                float* __restrict__ finePreB) {
  const int b = blockIdx.x >> 6, cc = blockIdx.x & 63;
  const int o = threadIdx.x;
  const int base = b * NN + cc * 64;
  const float* fb = feats + (size_t)b * NN * FO;
  float accA = 0.f, accB = 0.f;
#pragma unroll 8
  for (int q = 0; q < 64; ++q) {
    const int kk = base + q;
    const int j = jidxS[kk];
    const float fv = fb[(size_t)j * FO + o];
    accA = fmaf(alphaS[kk], fv, accA);
    accB = fmaf(betaS[kk], fv, accB);
    finePreA[(size_t)kk * FO + o] = accA;
    finePreB[(size_t)kk * FO + o] = accB;
  }
}

// ---------------- Kernel 4c: exclusive prefix over coarse sums --------------
__global__ __launch_bounds__(128) void k4c_coar(const float* __restrict__ finePreA,
                                                const float* __restrict__ finePreB,
                                                float* __restrict__ coarA,
                                                float* __restrict__ coarB) {
  const int b = blockIdx.x;
  const int o = threadIdx.x;
  float runA = 0.f, runB = 0.f;
#pragma unroll
  for (int c = 0; c < NCC; ++c) {
    coarA[(size_t)(b * (NCC + 1) + c) * FO + o] = runA;
    coarB[(size_t)(b * (NCC + 1) + c) * FO + o] = runB;
    runA += finePreA[(size_t)(b * NN + c * 64 + 63) * FO + o];
    runB += finePreB[(size_t)(b * NN + c * 64 + 63) * FO + o];
  }
  coarA[(size_t)(b * (NCC + 1) + NCC) * FO + o] = runA;   // total
  coarB[(size_t)(b * (NCC + 1) + NCC) * FO + o] = runB;
}

// ---------------- Kernel 5: streaming combine (no gathers) ------------------
// out[i,:] = E1_i*(totA - runA(kp_i)) + E2_i*runB(kp_i)
// runX(kp) = coarPref[kp>>6] + finePre[kp-1] (if kp not on chunk boundary).
__global__ __launch_bounds__(256) void k5_out(const float* __restrict__ finePreA,
                                              const float* __restrict__ finePreB,
                                              const float* __restrict__ coarA,
                                              const float* __restrict__ coarB,
                                              const int* __restrict__ kposA,
                                              const float* __restrict__ E1g,
                                              const float* __restrict__ E2g,
                                              float* __restrict__ out) {
  const int t = threadIdx.x;
  const int row = blockIdx.x * 2 + (t >> 7);
  const int o = t & 127;
  const int b = row >> 12;  // NN = 4096
  const int kp = kposA[row];
  const float e1 = E1g[row], e2 = E2g[row];
  const int c = kp >> 6;          // 0..64

  float runA = coarA[(size_t)(b * (NCC + 1) + c) * FO + o];
  float runB = coarB[(size_t)(b * (NCC + 1) + c) * FO + o];
  const float totA = coarA[(size_t)(b * (NCC + 1) + NCC) * FO + o];
  if (kp & 63) {
    runA += finePreA[(size_t)(b * NN + kp - 1) * FO + o];
    runB += finePreB[(size_t)(b * NN + kp - 1) * FO + o];
  }
  out[(size_t)row * FO + o] = fmaf(e1, totA - runA, e2 * runB);
}

extern "C" void kernel_launch(void* const* d_in, const int* in_sizes, int n_in,
                              void* d_out, int out_size, void* d_ws, size_t ws_size,
                              hipStream_t stream) {
  const float* x  = (const float*)d_in[0];
  const float* W  = (const float*)d_in[1];
  const float* wl = (const float*)d_in[2];
  const float* bl = (const float*)d_in[3];
  const float* wr = (const float*)d_in[4];
  const float* br = (const float*)d_in[5];
  float* out = (float*)d_out;

  float* ws = (float*)d_ws;
  float* feats    = ws; ws += NROW * FO;
  float* finePreA = ws; ws += NROW * FO;
  float* finePreB = ws; ws += NROW * FO;
  float* f1g      = ws; ws += NROW;
  float* f2g      = ws; ws += NROW;
  float* f1sort   = ws; ws += NROW;
  float* f2sort   = ws; ws += NROW;
  float* sc1      = ws; ws += NROW;
  float* sc2      = ws; ws += NROW;
  float* alphaS   = ws; ws += NROW;
  float* betaS    = ws; ws += NROW;
  float* E1g      = ws; ws += NROW;
  float* E2g      = ws; ws += NROW;
  int* jidxS      = (int*)ws; ws += NROW;
  int* kposA      = (int*)ws; ws += NROW;
  float* coarA    = ws; ws += NB * (NCC + 1) * FO;
  float* coarB    = ws; ws += NB * (NCC + 1) * FO;
  float* u_l      = ws; ws += KIN;
  float* u_r      = ws; ws += KIN;
  u16* whT  = (u16*)ws; ws += FO * KIN / 2;     // bf16 [128 col][256 k]
  u16* wloT = (u16*)ws; ws += FO * KIN / 2;
  (void)in_sizes; (void)n_in; (void)out_size; (void)ws_size;

  hipLaunchKernelGGL(k0_prep,  dim3(128),       dim3(256),  0, stream,
                     W, wl, wr, u_l, u_r, whT, wloT);
  hipLaunchKernelGGL(k1_fused, dim3(NROW / 64), dim3(256),  0, stream,
                     x, whT, wloT, u_l, u_r, bl, br, feats, f1g, f2g);
  hipLaunchKernelGGL(k3a_sort, dim3(8),         dim3(1024), 0, stream,
                     f1g, f2g, f1sort, sc1, sc2, f2sort, jidxS);
  hipLaunchKernelGGL(k3b_ab,   dim3(NB * 8),    dim3(512),  0, stream,
                     f1sort, sc1, sc2, f2sort, f1g, alphaS, betaS, kposA, E1g, E2g);
  hipLaunchKernelGGL(k4a_pref, dim3(NB * NCC),  dim3(128),  0, stream,
                     feats, alphaS, betaS, jidxS, finePreA, finePreB);
  hipLaunchKernelGGL(k4c_coar, dim3(NB),        dim3(128),  0, stream,
                     finePreA, finePreB, coarA, coarB);
  hipLaunchKernelGGL(k5_out,   dim3(NROW / 2),  dim3(256),  0, stream,
                     finePreA, finePreB, coarA, coarB, kposA, E1g, E2g, out);
}